// Round 1
// baseline (101.399 us; speedup 1.0000x reference)
//
#include <hip/hip_runtime.h>

namespace {

constexpr int T = 512;
constexpr int K = 4;
constexpr int G = 20000;
constexpr int EPG = 3;
constexpr int B = 512;
constexpr float SLOPE = 0.01f;  // jax.nn.leaky_relu default

__device__ __forceinline__ float lrelu(float x) { return x > 0.0f ? x : SLOPE * x; }

// Kernel 1: h2[b][t][k] = lrelu( sum_j lrelu(f*w1[t,j]+b1[t,j]) * w2[t,j,k] + b2[t,k] )
// thread = (b, t); coalesced feature reads, float4 param loads, float4 h2 writes.
__global__ __launch_bounds__(256) void h2_kernel(
    const float* __restrict__ features, const float* __restrict__ w1,
    const float* __restrict__ b1, const float* __restrict__ w2,
    const float* __restrict__ b2, float* __restrict__ h2out) {
  const int t = blockIdx.x * 256 + threadIdx.x;
  const int b = blockIdx.y;
  const float f = features[b * T + t];
  const float4 W1 = reinterpret_cast<const float4*>(w1)[t];
  const float4 B1 = reinterpret_cast<const float4*>(b1)[t];
  const float4 B2 = reinterpret_cast<const float4*>(b2)[t];
  const float h0 = lrelu(f * W1.x + B1.x);
  const float h1 = lrelu(f * W1.y + B1.y);
  const float h2 = lrelu(f * W1.z + B1.z);
  const float h3 = lrelu(f * W1.w + B1.w);
  const float4* W2 = reinterpret_cast<const float4*>(w2 + (size_t)t * (K * K));
  const float4 r0 = W2[0];  // w2[t][0][0..3]
  const float4 r1 = W2[1];
  const float4 r2 = W2[2];
  const float4 r3 = W2[3];
  float4 o;
  o.x = lrelu(B2.x + h0 * r0.x + h1 * r1.x + h2 * r2.x + h3 * r3.x);
  o.y = lrelu(B2.y + h0 * r0.y + h1 * r1.y + h2 * r2.y + h3 * r3.y);
  o.z = lrelu(B2.z + h0 * r0.z + h1 * r1.z + h2 * r2.z + h3 * r3.z);
  o.w = lrelu(B2.w + h0 * r0.w + h1 * r1.w + h2 * r2.w + h3 * r3.w);
  reinterpret_cast<float4*>(h2out)[b * T + t] = o;
}

// Kernel 2: out[b][g] = b3[g] + sum_e dot(h2[b][edge[g,e]][:], w3[g,e,:])
// Each thread owns GPT g's (w3/edge/b3 in registers, loaded ONCE), loops over a
// B-tile; per b the 8KB h2 row is staged in double-buffered LDS.
constexpr int GPT = 4;     // g's per thread -> 1024 g's per block
constexpr int BTILE = 16;  // b's per block

__global__ __launch_bounds__(256) void out_kernel(
    const float* __restrict__ h2, const float* __restrict__ w3,
    const float* __restrict__ b3, const int* __restrict__ edge,
    float* __restrict__ out) {
  __shared__ float4 row[2][T];  // 2 x 8KB
  const int tid = threadIdx.x;
  const int gbase = blockIdx.x * (GPT * 256);
  const int b0 = blockIdx.y * BTILE;

  int gg[GPT];
  int te[GPT][EPG];
  float4 w3v[GPT][EPG];
  float bias[GPT];
  bool valid[GPT];
#pragma unroll
  for (int i = 0; i < GPT; ++i) {
    const int g = gbase + i * 256 + tid;  // interleaved -> coalesced loads/stores
    gg[i] = g;
    valid[i] = (g < G);
    if (valid[i]) {
#pragma unroll
      for (int e = 0; e < EPG; ++e) te[i][e] = edge[g * EPG + e];
      // w3 row: 12 floats at byte offset g*48 -> 16B aligned, 3x float4
      const float4* wp = reinterpret_cast<const float4*>(w3 + (size_t)g * (EPG * K));
      w3v[i][0] = wp[0];
      w3v[i][1] = wp[1];
      w3v[i][2] = wp[2];
      bias[i] = b3[g];
    } else {
#pragma unroll
      for (int e = 0; e < EPG; ++e) te[i][e] = 0;
      w3v[i][0] = w3v[i][1] = w3v[i][2] = make_float4(0.f, 0.f, 0.f, 0.f);
      bias[i] = 0.f;
    }
  }

  // preload b0's row into buffer 0 (T=512 float4s, 2 per thread, coalesced)
  {
    const float4* src = reinterpret_cast<const float4*>(h2 + (size_t)b0 * T * K);
    row[0][tid] = src[tid];
    row[0][tid + 256] = src[tid + 256];
  }

  for (int ib = 0; ib < BTILE; ++ib) {
    const int cur = ib & 1;
    __syncthreads();  // row[cur] ready; also guards last iter's reads of row[cur^1]
    if (ib + 1 < BTILE) {
      const float4* src =
          reinterpret_cast<const float4*>(h2 + (size_t)(b0 + ib + 1) * T * K);
      row[cur ^ 1][tid] = src[tid];
      row[cur ^ 1][tid + 256] = src[tid + 256];
    }
    const int b = b0 + ib;
#pragma unroll
    for (int i = 0; i < GPT; ++i) {
      if (!valid[i]) continue;
      float acc = bias[i];
#pragma unroll
      for (int e = 0; e < EPG; ++e) {
        const float4 v = row[cur][te[i][e]];
        const float4 w = w3v[i][e];
        acc += v.x * w.x + v.y * w.y + v.z * w.z + v.w * w.w;
      }
      out[(size_t)b * G + gg[i]] = acc;  // coalesced across tid
    }
  }
}

}  // namespace

extern "C" void kernel_launch(void* const* d_in, const int* in_sizes, int n_in,
                              void* d_out, int out_size, void* d_ws, size_t ws_size,
                              hipStream_t stream) {
  const float* features = (const float*)d_in[0];
  const float* w1 = (const float*)d_in[1];
  const float* b1 = (const float*)d_in[2];
  const float* w2 = (const float*)d_in[3];
  const float* b2 = (const float*)d_in[4];
  const float* w3 = (const float*)d_in[5];
  const float* b3 = (const float*)d_in[6];
  const int* edge = (const int*)d_in[7];
  float* out = (float*)d_out;
  float* h2buf = (float*)d_ws;  // B*T*K*4 = 4 MB

  dim3 g1(T / 256, B);
  h2_kernel<<<g1, 256, 0, stream>>>(features, w1, b1, w2, b2, h2buf);

  dim3 g2((G + GPT * 256 - 1) / (GPT * 256), B / BTILE);
  out_kernel<<<g2, 256, 0, stream>>>(h2buf, w3, b3, edge, out);
}